// Round 1
// baseline (987.230 us; speedup 1.0000x reference)
//
#include <hip/hip_runtime.h>
#include <cstdint>
#include <cmath>

#define DIMM 1024
#define NHEAD 16
#define HEADD 64
#define CHUNKC 128
#define NBATCH 4
#define TLEN 4096
#define NCHUNK 32
#define BT (NBATCH * TLEN)      // 16384
#define NSTACK (5 * DIMM)       // 5120

typedef unsigned short ushort_t;
typedef __attribute__((ext_vector_type(8))) short short8;
typedef __attribute__((ext_vector_type(4))) float f32x4;

__device__ __forceinline__ float blo(unsigned int u) { return __uint_as_float(u << 16); }
__device__ __forceinline__ float bhi(unsigned int u) { return __uint_as_float(u & 0xffff0000u); }
__device__ __forceinline__ ushort_t f2bf(float f) {
  unsigned int u = __float_as_uint(f);
  u += 0x7fffu + ((u >> 16) & 1u);
  return (ushort_t)(u >> 16);
}
__device__ __forceinline__ float bf2f(ushort_t s) { return __uint_as_float(((unsigned int)s) << 16); }

__device__ __forceinline__ void async16(const ushort_t* g, ushort_t* l) {
  __builtin_amdgcn_global_load_lds((__attribute__((address_space(1))) void*)g,
                                   (__attribute__((address_space(3))) void*)l, 16, 0, 0);
}

// ---------------------------------------------------------------------------
// Kernel 1: cast x -> bf16, pack 5 weights -> stacked bf16 [5120][1024],
//           pack 5 biases -> fp32 [5120]
// ---------------------------------------------------------------------------
__global__ __launch_bounds__(256) void k_cast(
    const float* __restrict__ x,
    const float* __restrict__ Wq, const float* __restrict__ Wk,
    const float* __restrict__ Wv, const float* __restrict__ Wb, const float* __restrict__ Wa,
    const float* __restrict__ bq, const float* __restrict__ bk,
    const float* __restrict__ bv, const float* __restrict__ bb, const float* __restrict__ ba,
    ushort_t* __restrict__ xb, ushort_t* __restrict__ wbm, float* __restrict__ bias_st) {
  const long XU = (long)BT * DIMM / 4;       // 4194304 float4 units
  const long WU = (long)NSTACK * DIMM / 4;   // 1310720
  const long BU = NSTACK / 4;                // 1280
  const long NU = XU + WU + BU;
  for (long u = (long)blockIdx.x * blockDim.x + threadIdx.x; u < NU;
       u += (long)gridDim.x * blockDim.x) {
    if (u < XU) {
      float4 f = ((const float4*)x)[u];
      ushort4 o;
      o.x = f2bf(f.x); o.y = f2bf(f.y); o.z = f2bf(f.z); o.w = f2bf(f.w);
      ((ushort4*)xb)[u] = o;
    } else if (u < XU + WU) {
      long j = u - XU;
      long e = j * 4;
      int row = (int)(e >> 10);
      int col = (int)(e & 1023);
      int p = row >> 10, wr = row & 1023;
      const float* Wp = (p == 0) ? Wq : (p == 1) ? Wk : (p == 2) ? Wv : (p == 3) ? Wb : Wa;
      float4 f = *(const float4*)(Wp + (size_t)wr * DIMM + col);
      ushort4 o;
      o.x = f2bf(f.x); o.y = f2bf(f.y); o.z = f2bf(f.z); o.w = f2bf(f.w);
      ((ushort4*)wbm)[j] = o;
    } else {
      long j = u - XU - WU;
      int e = (int)(j * 4);
      int p = e >> 10, r = e & 1023;
      const float* bp = (p == 0) ? bq : (p == 1) ? bk : (p == 2) ? bv : (p == 3) ? bb : ba;
      ((float4*)bias_st)[j] = *(const float4*)(bp + r);
    }
  }
}

// ---------------------------------------------------------------------------
// Kernel 2: fused projection GEMM. out[m][n] = sum_k x[m][k]*Wst[n][k] + bias
// M=16384, N=5120, K=1024, bf16 MFMA 16x16x32, 128x128 tile, BK=32.
// Per-projection epilogue (block-uniform): q*scale, k*scale, v, softplus(beta),
// clip+sigmoid(alpha)->d_out.
// ---------------------------------------------------------------------------
__global__ __launch_bounds__(256) void k_proj(
    const ushort_t* __restrict__ xb, const ushort_t* __restrict__ wbm,
    const float* __restrict__ bias_st,
    ushort_t* __restrict__ qo, ushort_t* __restrict__ ko,
    ushort_t* __restrict__ vo, ushort_t* __restrict__ bo,
    float* __restrict__ ao) {
  __shared__ ushort_t As[128 * 32];
  __shared__ ushort_t Bs[128 * 32];
  const int tid = threadIdx.x;
  const int bn0 = blockIdx.x * 128;   // 0..5119 (8 tiles per projection)
  const int bm0 = blockIdx.y * 128;
  const int lane = tid & 63;
  const int wave = tid >> 6;
  const int quad = lane >> 4, lr = lane & 15;
  const int wr = (wave >> 1) * 64, wc = (wave & 1) * 64;

  f32x4 zero = {0.f, 0.f, 0.f, 0.f};
  f32x4 acc[4][4];
#pragma unroll
  for (int i = 0; i < 4; ++i)
#pragma unroll
    for (int j = 0; j < 4; ++j) acc[i][j] = zero;

  const int r0 = tid >> 2;
  const int c0 = (tid & 3) * 8;
  const ushort_t* ag0 = xb + (size_t)(bm0 + r0) * DIMM + c0;
  const ushort_t* ag1 = xb + (size_t)(bm0 + r0 + 64) * DIMM + c0;
  const ushort_t* bg0 = wbm + (size_t)(bn0 + r0) * DIMM + c0;
  const ushort_t* bg1 = wbm + (size_t)(bn0 + r0 + 64) * DIMM + c0;
  ushort_t* la0 = As + tid * 8;
  ushort_t* la1 = As + 2048 + tid * 8;
  ushort_t* lb0 = Bs + tid * 8;
  ushort_t* lb1 = Bs + 2048 + tid * 8;

  for (int kk = 0; kk < DIMM; kk += 32) {
    __syncthreads();
    async16(ag0 + kk, la0);
    async16(ag1 + kk, la1);
    async16(bg0 + kk, lb0);
    async16(bg1 + kk, lb1);
    __syncthreads();
    short8 af[4], bfr[4];
#pragma unroll
    for (int i = 0; i < 4; ++i)
      af[i] = *(const short8*)(As + (wr + i * 16 + lr) * 32 + quad * 8);
#pragma unroll
    for (int j = 0; j < 4; ++j)
      bfr[j] = *(const short8*)(Bs + (wc + j * 16 + lr) * 32 + quad * 8);
#pragma unroll
    for (int i = 0; i < 4; ++i)
#pragma unroll
      for (int j = 0; j < 4; ++j)
        acc[i][j] = __builtin_amdgcn_mfma_f32_16x16x32_bf16(af[i], bfr[j], acc[i][j], 0, 0, 0);
  }

  const int p = bn0 >> 10;          // projection id, block-uniform
  const int ncol0 = bn0 & 1023;
#pragma unroll
  for (int j = 0; j < 4; ++j) {
    const int colg = wc + j * 16 + lr;
    const float bias = bias_st[bn0 + colg];
    const int nc = ncol0 + colg;
#pragma unroll
    for (int i = 0; i < 4; ++i) {
#pragma unroll
      for (int r = 0; r < 4; ++r) {
        const int rowl = wr + i * 16 + quad * 4 + r;
        const size_t o = (size_t)(bm0 + rowl) * DIMM + nc;
        float val = acc[i][j][r] + bias;
        if (p == 0) {
          qo[o] = f2bf(val * 0.125f);
        } else if (p == 1) {
          ko[o] = f2bf(val * 0.125f);
        } else if (p == 2) {
          vo[o] = f2bf(val);
        } else if (p == 3) {
          float sp = (val > 20.f) ? val : log1pf(expf(val));
          bo[o] = f2bf(sp);
        } else {
          float c = fminf(fmaxf(val, -10.f), 10.f);
          ao[o] = 1.f / (1.f + expf(-c));
        }
      }
    }
  }
}

// ---------------------------------------------------------------------------
// Kernel 3: per-(b,n,h) stats. la_mean = mean_d log(alpha_val), inclusive
// cumsum over c -> m; bmean = mean_d beta; asum = exp(m[127]).
// ---------------------------------------------------------------------------
__global__ __launch_bounds__(128) void k_stats(
    const float* __restrict__ alpha, const ushort_t* __restrict__ betaw,
    float* __restrict__ mArr, float* __restrict__ bmean, float* __restrict__ asum) {
  const int bnh = blockIdx.x;
  const int h = bnh & 15, n = (bnh >> 4) & 31, b = bnh >> 9;
  const int c = threadIdx.x;
  const size_t bt = (size_t)b * TLEN + n * CHUNKC + c;

  const float4* ap = (const float4*)(alpha + bt * DIMM + h * HEADD);
  float ls = 0.f;
#pragma unroll
  for (int w = 0; w < 16; ++w) {
    float4 a = ap[w];
    ls += logf(a.x) + logf(a.y) + logf(a.z) + logf(a.w);
  }
  const uint4* bp = (const uint4*)(betaw + bt * DIMM + h * HEADD);
  float bs = 0.f;
#pragma unroll
  for (int w = 0; w < 8; ++w) {
    uint4 u = bp[w];
    bs += blo(u.x) + bhi(u.x) + blo(u.y) + bhi(u.y) + blo(u.z) + bhi(u.z) + blo(u.w) + bhi(u.w);
  }
  float la = ls * (1.f / 64.f);

  __shared__ float s[128];
  s[c] = la;
  __syncthreads();
  for (int off = 1; off < 128; off <<= 1) {
    float t = (c >= off) ? s[c - off] : 0.f;
    __syncthreads();
    s[c] += t;
    __syncthreads();
  }
  float m = s[c];
  const size_t o = (size_t)bnh * CHUNKC + c;
  mArr[o] = m;
  bmean[o] = bs * (1.f / 64.f);
  if (c == 127) asum[bnh] = expf(m);
}

// ---------------------------------------------------------------------------
// Kernel 4: delta[b,n,h,kd,vd] = sum_c k[c,kd]*v[c,vd]*bmean[c]
// ---------------------------------------------------------------------------
__global__ __launch_bounds__(256) void k_delta(
    const ushort_t* __restrict__ kw, const ushort_t* __restrict__ vw,
    const float* __restrict__ bmean, float* __restrict__ delta) {
  __shared__ ushort_t kc[8192];
  __shared__ ushort_t vc[8192];
  __shared__ float bm[128];
  const int bnh = blockIdx.x;
  const int h = bnh & 15, n = (bnh >> 4) & 31, b = bnh >> 9;
  const int tid = threadIdx.x;
  const size_t bt0 = (size_t)b * TLEN + n * CHUNKC;

#pragma unroll
  for (int it = 0; it < 4; ++it) {
    int u = tid + it * 256;          // 0..1023 uint4 units
    int row = u >> 3, col = (u & 7) * 8;
    size_t go = (bt0 + row) * DIMM + h * HEADD + col;
    ((uint4*)kc)[u] = *(const uint4*)(kw + go);
    ((uint4*)vc)[u] = *(const uint4*)(vw + go);
  }
  if (tid < 128) bm[tid] = bmean[(size_t)bnh * CHUNKC + tid];
  __syncthreads();

  const int kd = tid >> 2, v0 = (tid & 3) * 16;
  float acc[16];
#pragma unroll
  for (int l = 0; l < 16; ++l) acc[l] = 0.f;

#pragma unroll 4
  for (int c = 0; c < 128; ++c) {
    float kb = bf2f(kc[c * 64 + kd]) * bm[c];
    const uint4* vr = (const uint4*)(vc + c * 64 + v0);
    uint4 u0 = vr[0], u1 = vr[1];
    acc[0] += kb * blo(u0.x);  acc[1] += kb * bhi(u0.x);
    acc[2] += kb * blo(u0.y);  acc[3] += kb * bhi(u0.y);
    acc[4] += kb * blo(u0.z);  acc[5] += kb * bhi(u0.z);
    acc[6] += kb * blo(u0.w);  acc[7] += kb * bhi(u0.w);
    acc[8] += kb * blo(u1.x);  acc[9] += kb * bhi(u1.x);
    acc[10] += kb * blo(u1.y); acc[11] += kb * bhi(u1.y);
    acc[12] += kb * blo(u1.z); acc[13] += kb * bhi(u1.z);
    acc[14] += kb * blo(u1.w); acc[15] += kb * bhi(u1.w);
  }
  float* dst = delta + (size_t)bnh * 4096 + kd * 64 + v0;
#pragma unroll
  for (int l4 = 0; l4 < 4; ++l4)
    ((float4*)dst)[l4] = make_float4(acc[l4 * 4], acc[l4 * 4 + 1], acc[l4 * 4 + 2], acc[l4 * 4 + 3]);
}

// ---------------------------------------------------------------------------
// Kernel 5: sequential scan over chunks per (b,h). E_n = state entering chunk n.
// E_{n+1} = E_n * asum_n + delta_n. Final state -> d_out.
// ---------------------------------------------------------------------------
__global__ __launch_bounds__(256) void k_scan(
    const float* __restrict__ delta, const float* __restrict__ asum,
    float* __restrict__ Earr, float* __restrict__ state_out) {
  const int b = blockIdx.x >> 4, h = blockIdx.x & 15;
  const int tid = threadIdx.x;
  float e[16];
#pragma unroll
  for (int l = 0; l < 16; ++l) e[l] = 0.f;

  for (int n = 0; n < 32; ++n) {
    const size_t o = (((size_t)b * 32 + n) * 16 + h) * 4096 + (size_t)tid * 16;
    const float a = asum[((size_t)b * 32 + n) * 16 + h];
    float4* Eo = (float4*)(Earr + o);
    const float4* dp = (const float4*)(delta + o);
#pragma unroll
    for (int l4 = 0; l4 < 4; ++l4) {
      Eo[l4] = make_float4(e[l4 * 4], e[l4 * 4 + 1], e[l4 * 4 + 2], e[l4 * 4 + 3]);
      float4 dv = dp[l4];
      e[l4 * 4 + 0] = e[l4 * 4 + 0] * a + dv.x;
      e[l4 * 4 + 1] = e[l4 * 4 + 1] * a + dv.y;
      e[l4 * 4 + 2] = e[l4 * 4 + 2] * a + dv.z;
      e[l4 * 4 + 3] = e[l4 * 4 + 3] * a + dv.w;
    }
  }
  float4* so = (float4*)(state_out + (size_t)(b * 16 + h) * 4096 + (size_t)tid * 16);
#pragma unroll
  for (int l4 = 0; l4 < 4; ++l4)
    so[l4] = make_float4(e[l4 * 4], e[l4 * 4 + 1], e[l4 * 4 + 2], e[l4 * 4 + 3]);
}

// ---------------------------------------------------------------------------
// Kernel 6: y[b,n,c,h,:] = (q_c @ E_n)*exp(m_c)
//                        + sum_{j<=c} (q_c . k_j) * exp(m_c - m_j) * (v*beta)_j
// One block per (b,n,h), 128 threads = one row each.
// ---------------------------------------------------------------------------
__global__ __launch_bounds__(128) void k_y(
    const ushort_t* __restrict__ qw, const ushort_t* __restrict__ kw,
    const ushort_t* __restrict__ vw, const ushort_t* __restrict__ betaw,
    const float* __restrict__ mArr, const float* __restrict__ Earr,
    float* __restrict__ yout) {
  __shared__ ushort_t kc[8192];
  __shared__ ushort_t vbc[8192];
  __shared__ float El[4096];
  __shared__ float ml[128];
  const int bnh = blockIdx.x;
  const int h = bnh & 15, n = (bnh >> 4) & 31, b = bnh >> 9;
  const int tid = threadIdx.x;   // row i
  const size_t bt0 = (size_t)b * TLEN + n * CHUNKC;

#pragma unroll
  for (int it = 0; it < 8; ++it) {
    int u = tid + it * 128;       // 0..1023 uint4 units
    int row = u >> 3, col = (u & 7) * 8;
    size_t go = (bt0 + row) * DIMM + h * HEADD + col;
    ((uint4*)kc)[u] = *(const uint4*)(kw + go);
    uint4 vv = *(const uint4*)(vw + go);
    uint4 bb2 = *(const uint4*)(betaw + go);
    uint4 r;
    r.x = (unsigned)f2bf(blo(vv.x) * blo(bb2.x)) | ((unsigned)f2bf(bhi(vv.x) * bhi(bb2.x)) << 16);
    r.y = (unsigned)f2bf(blo(vv.y) * blo(bb2.y)) | ((unsigned)f2bf(bhi(vv.y) * bhi(bb2.y)) << 16);
    r.z = (unsigned)f2bf(blo(vv.z) * blo(bb2.z)) | ((unsigned)f2bf(bhi(vv.z) * bhi(bb2.z)) << 16);
    r.w = (unsigned)f2bf(blo(vv.w) * blo(bb2.w)) | ((unsigned)f2bf(bhi(vv.w) * bhi(bb2.w)) << 16);
    ((uint4*)vbc)[u] = r;
  }
  const float4* Eg = (const float4*)(Earr + (size_t)bnh * 4096);
#pragma unroll
  for (int it = 0; it < 8; ++it) ((float4*)El)[tid + it * 128] = Eg[tid + it * 128];
  ml[tid] = mArr[(size_t)bnh * CHUNKC + tid];
  __syncthreads();

  const int i = tid;
  float qf[64];
  const uint4* qp4 = (const uint4*)(qw + (bt0 + i) * DIMM + h * HEADD);
#pragma unroll
  for (int w = 0; w < 8; ++w) {
    uint4 u = qp4[w];
    qf[w * 8 + 0] = blo(u.x); qf[w * 8 + 1] = bhi(u.x);
    qf[w * 8 + 2] = blo(u.y); qf[w * 8 + 3] = bhi(u.y);
    qf[w * 8 + 4] = blo(u.z); qf[w * 8 + 5] = bhi(u.z);
    qf[w * 8 + 6] = blo(u.w); qf[w * 8 + 7] = bhi(u.w);
  }

  float y[64];
#pragma unroll
  for (int g = 0; g < 64; ++g) y[g] = 0.f;

  // mem = q_i @ E  (all lanes broadcast-read same E row)
  const float4* El4 = (const float4*)El;
#pragma unroll
  for (int qd = 0; qd < 64; ++qd) {
    float qv = qf[qd];
#pragma unroll
    for (int g = 0; g < 16; ++g) {
      float4 ev = El4[qd * 16 + g];
      y[g * 4 + 0] += qv * ev.x;
      y[g * 4 + 1] += qv * ev.y;
      y[g * 4 + 2] += qv * ev.z;
      y[g * 4 + 3] += qv * ev.w;
    }
  }
  const float mi = ml[i];
  const float ci = __expf(mi);
#pragma unroll
  for (int g = 0; g < 64; ++g) y[g] *= ci;

  // intra-chunk attention, j <= i
  for (int j = 0; j <= i; ++j) {
    const uint4* kr = (const uint4*)(kc + j * 64);
    float s = 0.f;
#pragma unroll
    for (int w = 0; w < 8; ++w) {
      uint4 u = kr[w];
      s += qf[w * 8 + 0] * blo(u.x) + qf[w * 8 + 1] * bhi(u.x)
         + qf[w * 8 + 2] * blo(u.y) + qf[w * 8 + 3] * bhi(u.y)
         + qf[w * 8 + 4] * blo(u.z) + qf[w * 8 + 5] * bhi(u.z)
         + qf[w * 8 + 6] * blo(u.w) + qf[w * 8 + 7] * bhi(u.w);
    }
    const float wgt = s * __expf(mi - ml[j]);
    const uint4* vr = (const uint4*)(vbc + j * 64);
#pragma unroll
    for (int w = 0; w < 8; ++w) {
      uint4 u = vr[w];
      y[w * 8 + 0] += wgt * blo(u.x); y[w * 8 + 1] += wgt * bhi(u.x);
      y[w * 8 + 2] += wgt * blo(u.y); y[w * 8 + 3] += wgt * bhi(u.y);
      y[w * 8 + 4] += wgt * blo(u.z); y[w * 8 + 5] += wgt * bhi(u.z);
      y[w * 8 + 6] += wgt * blo(u.w); y[w * 8 + 7] += wgt * bhi(u.w);
    }
  }

  float* yo = yout + (bt0 + i) * DIMM + h * HEADD;
#pragma unroll
  for (int g = 0; g < 16; ++g)
    ((float4*)yo)[g] = make_float4(y[4 * g], y[4 * g + 1], y[4 * g + 2], y[4 * g + 3]);
}

// ---------------------------------------------------------------------------
extern "C" void kernel_launch(void* const* d_in, const int* in_sizes, int n_in,
                              void* d_out, int out_size, void* d_ws, size_t ws_size,
                              hipStream_t stream) {
  const float* x  = (const float*)d_in[0];
  const float* Wq = (const float*)d_in[1];
  const float* bq = (const float*)d_in[2];
  const float* Wk = (const float*)d_in[3];
  const float* bk = (const float*)d_in[4];
  const float* Wv = (const float*)d_in[5];
  const float* bv = (const float*)d_in[6];
  const float* Wb = (const float*)d_in[7];
  const float* bb = (const float*)d_in[8];
  const float* Wa = (const float*)d_in[9];
  const float* ba = (const float*)d_in[10];

  char* ws = (char*)d_ws;
  ushort_t* xb   = (ushort_t*)(ws + 0);           // 33554432 B
  ushort_t* wbm  = (ushort_t*)(ws + 33554432);    // 10485760 B
  float* bias_st = (float*)(ws + 44040192);       // 20480 B
  ushort_t* qw   = (ushort_t*)(ws + 44060672);    // 33554432 B
  ushort_t* kw   = (ushort_t*)(ws + 77615104);    // 33554432 B
  ushort_t* vw   = (ushort_t*)(ws + 111169536);   // 33554432 B
  ushort_t* bw   = (ushort_t*)(ws + 144723968);   // 33554432 B
  float* mArr    = (float*)(ws + 178278400);      // 1048576 B
  float* bmean   = (float*)(ws + 179326976);      // 1048576 B
  float* asum    = (float*)(ws + 180375552);      // 8192 B
  float* delta   = (float*)(ws + 180383744);      // 33554432 B
  float* Earr    = (float*)(ws + 213938176);      // 33554432 B  (total 247492608)

  float* yout = (float*)d_out;
  float* state_out = yout + (size_t)BT * DIMM;                 // + 16777216
  float* aout = state_out + (size_t)NBATCH * NHEAD * 64 * 64;  // + 262144

  k_cast<<<dim3(4096), dim3(256), 0, stream>>>(x, Wq, Wk, Wv, Wb, Wa,
                                               bq, bk, bv, bb, ba, xb, wbm, bias_st);
  k_proj<<<dim3(40, 128), dim3(256), 0, stream>>>(xb, wbm, bias_st, qw, kw, vw, bw, aout);
  k_stats<<<dim3(2048), dim3(128), 0, stream>>>(aout, bw, mArr, bmean, asum);
  k_delta<<<dim3(2048), dim3(256), 0, stream>>>(kw, vw, bmean, delta);
  k_scan<<<dim3(64), dim3(256), 0, stream>>>(delta, asum, Earr, state_out);
  k_y<<<dim3(2048), dim3(128), 0, stream>>>(qw, kw, vw, bw, mArr, Earr, yout);
}

// Round 2
// 671.741 us; speedup vs baseline: 1.4697x; 1.4697x over previous
//
#include <hip/hip_runtime.h>
#include <cstdint>
#include <cmath>

#define DIMM 1024
#define NHEAD 16
#define HEADD 64
#define CHUNKC 128
#define NBATCH 4
#define TLEN 4096
#define NCHUNK 32
#define BT (NBATCH * TLEN)      // 16384
#define NSTACK (5 * DIMM)       // 5120

typedef unsigned short ushort_t;
typedef __attribute__((ext_vector_type(8))) short short8;
typedef __attribute__((ext_vector_type(4))) float f32x4;

__device__ __forceinline__ float blo(unsigned int u) { return __uint_as_float(u << 16); }
__device__ __forceinline__ float bhi(unsigned int u) { return __uint_as_float(u & 0xffff0000u); }
__device__ __forceinline__ ushort_t f2bf(float f) {
  unsigned int u = __float_as_uint(f);
  u += 0x7fffu + ((u >> 16) & 1u);
  return (ushort_t)(u >> 16);
}
__device__ __forceinline__ float bf2f(ushort_t s) { return __uint_as_float(((unsigned int)s) << 16); }
__device__ __forceinline__ unsigned pack2(float a, float b) {
  return (unsigned)f2bf(a) | ((unsigned)f2bf(b) << 16);
}

__device__ __forceinline__ void async16(const ushort_t* g, ushort_t* l) {
  __builtin_amdgcn_global_load_lds((__attribute__((address_space(1))) void*)g,
                                   (__attribute__((address_space(3))) void*)l, 16, 0, 0);
}

// ---------------------------------------------------------------------------
// Kernel 1: cast x -> bf16, pack 5 weights -> stacked bf16 [5120][1024],
//           pack 5 biases -> fp32 [5120]
// ---------------------------------------------------------------------------
__global__ __launch_bounds__(256) void k_cast(
    const float* __restrict__ x,
    const float* __restrict__ Wq, const float* __restrict__ Wk,
    const float* __restrict__ Wv, const float* __restrict__ Wb, const float* __restrict__ Wa,
    const float* __restrict__ bq, const float* __restrict__ bk,
    const float* __restrict__ bv, const float* __restrict__ bb, const float* __restrict__ ba,
    ushort_t* __restrict__ xb, ushort_t* __restrict__ wbm, float* __restrict__ bias_st) {
  const long XU = (long)BT * DIMM / 4;       // 4194304 float4 units
  const long WU = (long)NSTACK * DIMM / 4;   // 1310720
  const long BU = NSTACK / 4;                // 1280
  const long NU = XU + WU + BU;
  for (long u = (long)blockIdx.x * blockDim.x + threadIdx.x; u < NU;
       u += (long)gridDim.x * blockDim.x) {
    if (u < XU) {
      float4 f = ((const float4*)x)[u];
      ushort4 o;
      o.x = f2bf(f.x); o.y = f2bf(f.y); o.z = f2bf(f.z); o.w = f2bf(f.w);
      ((ushort4*)xb)[u] = o;
    } else if (u < XU + WU) {
      long j = u - XU;
      long e = j * 4;
      int row = (int)(e >> 10);
      int col = (int)(e & 1023);
      int p = row >> 10, wr = row & 1023;
      const float* Wp = (p == 0) ? Wq : (p == 1) ? Wk : (p == 2) ? Wv : (p == 3) ? Wb : Wa;
      float4 f = *(const float4*)(Wp + (size_t)wr * DIMM + col);
      ushort4 o;
      o.x = f2bf(f.x); o.y = f2bf(f.y); o.z = f2bf(f.z); o.w = f2bf(f.w);
      ((ushort4*)wbm)[j] = o;
    } else {
      long j = u - XU - WU;
      int e = (int)(j * 4);
      int p = e >> 10, r = e & 1023;
      const float* bp = (p == 0) ? bq : (p == 1) ? bk : (p == 2) ? bv : (p == 3) ? bb : ba;
      ((float4*)bias_st)[j] = *(const float4*)(bp + r);
    }
  }
}

// ---------------------------------------------------------------------------
// Kernel 2: fused projection GEMM. out[m][n] = sum_k x[m][k]*Wst[n][k] + bias
// M=16384, N=5120, K=1024, bf16 MFMA 16x16x32, 128x128 tile, BK=32.
// ---------------------------------------------------------------------------
__global__ __launch_bounds__(256) void k_proj(
    const ushort_t* __restrict__ xb, const ushort_t* __restrict__ wbm,
    const float* __restrict__ bias_st,
    ushort_t* __restrict__ qo, ushort_t* __restrict__ ko,
    ushort_t* __restrict__ vo, ushort_t* __restrict__ bo,
    float* __restrict__ ao) {
  __shared__ ushort_t As[128 * 32];
  __shared__ ushort_t Bs[128 * 32];
  const int tid = threadIdx.x;
  const int bn0 = blockIdx.x * 128;   // 0..5119 (8 tiles per projection)
  const int bm0 = blockIdx.y * 128;
  const int lane = tid & 63;
  const int wave = tid >> 6;
  const int quad = lane >> 4, lr = lane & 15;
  const int wr = (wave >> 1) * 64, wc = (wave & 1) * 64;

  f32x4 zero = {0.f, 0.f, 0.f, 0.f};
  f32x4 acc[4][4];
#pragma unroll
  for (int i = 0; i < 4; ++i)
#pragma unroll
    for (int j = 0; j < 4; ++j) acc[i][j] = zero;

  const int r0 = tid >> 2;
  const int c0 = (tid & 3) * 8;
  const ushort_t* ag0 = xb + (size_t)(bm0 + r0) * DIMM + c0;
  const ushort_t* ag1 = xb + (size_t)(bm0 + r0 + 64) * DIMM + c0;
  const ushort_t* bg0 = wbm + (size_t)(bn0 + r0) * DIMM + c0;
  const ushort_t* bg1 = wbm + (size_t)(bn0 + r0 + 64) * DIMM + c0;
  ushort_t* la0 = As + tid * 8;
  ushort_t* la1 = As + 2048 + tid * 8;
  ushort_t* lb0 = Bs + tid * 8;
  ushort_t* lb1 = Bs + 2048 + tid * 8;

  for (int kk = 0; kk < DIMM; kk += 32) {
    __syncthreads();
    async16(ag0 + kk, la0);
    async16(ag1 + kk, la1);
    async16(bg0 + kk, lb0);
    async16(bg1 + kk, lb1);
    __syncthreads();
    short8 af[4], bfr[4];
#pragma unroll
    for (int i = 0; i < 4; ++i)
      af[i] = *(const short8*)(As + (wr + i * 16 + lr) * 32 + quad * 8);
#pragma unroll
    for (int j = 0; j < 4; ++j)
      bfr[j] = *(const short8*)(Bs + (wc + j * 16 + lr) * 32 + quad * 8);
#pragma unroll
    for (int i = 0; i < 4; ++i)
#pragma unroll
      for (int j = 0; j < 4; ++j)
        acc[i][j] = __builtin_amdgcn_mfma_f32_16x16x32_bf16(af[i], bfr[j], acc[i][j], 0, 0, 0);
  }

  const int p = bn0 >> 10;          // projection id, block-uniform
  const int ncol0 = bn0 & 1023;
#pragma unroll
  for (int j = 0; j < 4; ++j) {
    const int colg = wc + j * 16 + lr;
    const float bias = bias_st[bn0 + colg];
    const int nc = ncol0 + colg;
#pragma unroll
    for (int i = 0; i < 4; ++i) {
#pragma unroll
      for (int r = 0; r < 4; ++r) {
        const int rowl = wr + i * 16 + quad * 4 + r;
        const size_t o = (size_t)(bm0 + rowl) * DIMM + nc;
        float val = acc[i][j][r] + bias;
        if (p == 0) {
          qo[o] = f2bf(val * 0.125f);
        } else if (p == 1) {
          ko[o] = f2bf(val * 0.125f);
        } else if (p == 2) {
          vo[o] = f2bf(val);
        } else if (p == 3) {
          float sp = (val > 20.f) ? val : log1pf(expf(val));
          bo[o] = f2bf(sp);
        } else {
          float c = fminf(fmaxf(val, -10.f), 10.f);
          ao[o] = 1.f / (1.f + expf(-c));
        }
      }
    }
  }
}

// ---------------------------------------------------------------------------
// Kernel 3: per-(b,n,h) stats.
// ---------------------------------------------------------------------------
__global__ __launch_bounds__(128) void k_stats(
    const float* __restrict__ alpha, const ushort_t* __restrict__ betaw,
    float* __restrict__ mArr, float* __restrict__ bmean, float* __restrict__ asum) {
  const int bnh = blockIdx.x;
  const int h = bnh & 15, n = (bnh >> 4) & 31, b = bnh >> 9;
  const int c = threadIdx.x;
  const size_t bt = (size_t)b * TLEN + n * CHUNKC + c;

  const float4* ap = (const float4*)(alpha + bt * DIMM + h * HEADD);
  float ls = 0.f;
#pragma unroll
  for (int w = 0; w < 16; ++w) {
    float4 a = ap[w];
    ls += logf(a.x) + logf(a.y) + logf(a.z) + logf(a.w);
  }
  const uint4* bp = (const uint4*)(betaw + bt * DIMM + h * HEADD);
  float bs = 0.f;
#pragma unroll
  for (int w = 0; w < 8; ++w) {
    uint4 u = bp[w];
    bs += blo(u.x) + bhi(u.x) + blo(u.y) + bhi(u.y) + blo(u.z) + bhi(u.z) + blo(u.w) + bhi(u.w);
  }
  float la = ls * (1.f / 64.f);

  __shared__ float s[128];
  s[c] = la;
  __syncthreads();
  for (int off = 1; off < 128; off <<= 1) {
    float t = (c >= off) ? s[c - off] : 0.f;
    __syncthreads();
    s[c] += t;
    __syncthreads();
  }
  float m = s[c];
  const size_t o = (size_t)bnh * CHUNKC + c;
  mArr[o] = m;
  bmean[o] = bs * (1.f / 64.f);
  if (c == 127) asum[bnh] = expf(m);
}

// ---------------------------------------------------------------------------
// Kernel 4: delta[b,n,h,kd,vd] = sum_c k[c,kd]*v[c,vd]*bmean[c]
// ---------------------------------------------------------------------------
__global__ __launch_bounds__(256) void k_delta(
    const ushort_t* __restrict__ kw, const ushort_t* __restrict__ vw,
    const float* __restrict__ bmean, float* __restrict__ delta) {
  __shared__ ushort_t kc[8192];
  __shared__ ushort_t vc[8192];
  __shared__ float bm[128];
  const int bnh = blockIdx.x;
  const int h = bnh & 15, n = (bnh >> 4) & 31, b = bnh >> 9;
  const int tid = threadIdx.x;
  const size_t bt0 = (size_t)b * TLEN + n * CHUNKC;

#pragma unroll
  for (int it = 0; it < 4; ++it) {
    int u = tid + it * 256;
    int row = u >> 3, col = (u & 7) * 8;
    size_t go = (bt0 + row) * DIMM + h * HEADD + col;
    ((uint4*)kc)[u] = *(const uint4*)(kw + go);
    ((uint4*)vc)[u] = *(const uint4*)(vw + go);
  }
  if (tid < 128) bm[tid] = bmean[(size_t)bnh * CHUNKC + tid];
  __syncthreads();

  const int kd = tid >> 2, v0 = (tid & 3) * 16;
  float acc[16];
#pragma unroll
  for (int l = 0; l < 16; ++l) acc[l] = 0.f;

#pragma unroll 4
  for (int c = 0; c < 128; ++c) {
    float kb = bf2f(kc[c * 64 + kd]) * bm[c];
    const uint4* vr = (const uint4*)(vc + c * 64 + v0);
    uint4 u0 = vr[0], u1 = vr[1];
    acc[0] += kb * blo(u0.x);  acc[1] += kb * bhi(u0.x);
    acc[2] += kb * blo(u0.y);  acc[3] += kb * bhi(u0.y);
    acc[4] += kb * blo(u0.z);  acc[5] += kb * bhi(u0.z);
    acc[6] += kb * blo(u0.w);  acc[7] += kb * bhi(u0.w);
    acc[8] += kb * blo(u1.x);  acc[9] += kb * bhi(u1.x);
    acc[10] += kb * blo(u1.y); acc[11] += kb * bhi(u1.y);
    acc[12] += kb * blo(u1.z); acc[13] += kb * bhi(u1.z);
    acc[14] += kb * blo(u1.w); acc[15] += kb * bhi(u1.w);
  }
  float* dst = delta + (size_t)bnh * 4096 + kd * 64 + v0;
#pragma unroll
  for (int l4 = 0; l4 < 4; ++l4)
    ((float4*)dst)[l4] = make_float4(acc[l4 * 4], acc[l4 * 4 + 1], acc[l4 * 4 + 2], acc[l4 * 4 + 3]);
}

// ---------------------------------------------------------------------------
// Kernel 5: scan over chunks. 1024 blocks: (b,h,group of 256 state elems).
// E_{n+1} = E_n * asum_n + delta_n. Entry states -> Earr; final -> state_out.
// ---------------------------------------------------------------------------
__global__ __launch_bounds__(256) void k_scan(
    const float* __restrict__ delta, const float* __restrict__ asum,
    float* __restrict__ Earr, float* __restrict__ state_out) {
  const int bh = blockIdx.x >> 4;        // b*16+h
  const int g = blockIdx.x & 15;
  const int b = bh >> 4, h = bh & 15;
  const int elem = g * 256 + threadIdx.x;
  float e = 0.f;
  for (int n = 0; n < 32; ++n) {
    const size_t o = (((size_t)b * 32 + n) * 16 + h) * 4096 + elem;
    const float a = asum[((size_t)b * 32 + n) * 16 + h];
    Earr[o] = e;
    e = e * a + delta[o];
  }
  state_out[(size_t)bh * 4096 + elem] = e;
}

// ---------------------------------------------------------------------------
// Kernel 6 (MFMA rewrite): per (b,n,h) block, 256 threads = 4 waves.
// GEMM1: S = q k^T (128x128x64), decay+mask in C-layout, P staged per-wave
// in LDS (A-layout round trip). GEMM2: y = P_ext @ Vb_ext, K=192 where
// columns 128..191 carry the inter-chunk memory term: P[i][128+kd] =
// q[i][kd]*exp(m_i), Vb_ext[128+kd][vd] = E[kd][vd].
// q/k fragments are read directly from global (L1-served, 4-wave reuse).
// ---------------------------------------------------------------------------
__global__ __launch_bounds__(256) void k_y(
    const ushort_t* __restrict__ qw, const ushort_t* __restrict__ kw,
    const ushort_t* __restrict__ vw, const ushort_t* __restrict__ betaw,
    const float* __restrict__ mArr, const float* __restrict__ Earr,
    float* __restrict__ yout) {
  // VbT[vd][j'] : j' in [0,192): 0..127 = (v*beta)^T, 128..191 = E^T column kd
  __shared__ __align__(16) ushort_t vbt[64][200];   // 25600 B (stride 400B: 2-way max)
  __shared__ __align__(16) ushort_t pst[4][32][40]; // 10240 B per-wave P staging
  __shared__ float ms[128];                         // 512 B
  const int bnh = blockIdx.x;
  const int h = bnh & 15, n = (bnh >> 4) & 31, b = bnh >> 9;
  const int tid = threadIdx.x;
  const int lane = tid & 63;
  const int wv = tid >> 6;
  const int quad = lane >> 4, lr = lane & 15;
  const int i0 = wv * 32;
  const size_t bt0 = (size_t)b * TLEN + n * CHUNKC;
  const size_t hoff = (size_t)h * HEADD;

  // ---- Phase A: stage VbT (v*beta transposed) + E^T + m ----
#pragma unroll
  for (int it = 0; it < 4; ++it) {
    int u = tid + it * 256;          // 0..1023
    int j = u & 127, vd0 = (u >> 7) * 8;
    size_t go = (bt0 + j) * DIMM + hoff + vd0;
    uint4 vv = *(const uint4*)(vw + go);
    uint4 bb2 = *(const uint4*)(betaw + go);
    vbt[vd0 + 0][j] = f2bf(blo(vv.x) * blo(bb2.x));
    vbt[vd0 + 1][j] = f2bf(bhi(vv.x) * bhi(bb2.x));
    vbt[vd0 + 2][j] = f2bf(blo(vv.y) * blo(bb2.y));
    vbt[vd0 + 3][j] = f2bf(bhi(vv.y) * bhi(bb2.y));
    vbt[vd0 + 4][j] = f2bf(blo(vv.z) * blo(bb2.z));
    vbt[vd0 + 5][j] = f2bf(bhi(vv.z) * bhi(bb2.z));
    vbt[vd0 + 6][j] = f2bf(blo(vv.w) * blo(bb2.w));
    vbt[vd0 + 7][j] = f2bf(bhi(vv.w) * bhi(bb2.w));
  }
  const float4* Eg = (const float4*)(Earr + (size_t)bnh * 4096);
#pragma unroll
  for (int it = 0; it < 4; ++it) {
    int u = tid + it * 256;          // 0..1023 float4 units
    int kd = u >> 4, vd0 = (u & 15) * 4;
    float4 ev = Eg[u];
    vbt[vd0 + 0][128 + kd] = f2bf(ev.x);
    vbt[vd0 + 1][128 + kd] = f2bf(ev.y);
    vbt[vd0 + 2][128 + kd] = f2bf(ev.z);
    vbt[vd0 + 3][128 + kd] = f2bf(ev.w);
  }
  if (tid < 128) ms[tid] = mArr[(size_t)bnh * CHUNKC + tid];
  __syncthreads();

  // ---- per-lane q A-fragments (from global) + row decay consts ----
  short8 qa[2][2];
#pragma unroll
  for (int it = 0; it < 2; ++it) {
    const ushort_t* qg = qw + (bt0 + i0 + it * 16 + lr) * DIMM + hoff + quad * 8;
    qa[it][0] = *(const short8*)(qg);
    qa[it][1] = *(const short8*)(qg + 32);
  }
  float mi[2][4];
#pragma unroll
  for (int it = 0; it < 2; ++it)
#pragma unroll
    for (int r = 0; r < 4; ++r) mi[it][r] = ms[i0 + it * 16 + quad * 4 + r];

  f32x4 zero = {0.f, 0.f, 0.f, 0.f};
  f32x4 acc2[2][4];
#pragma unroll
  for (int it = 0; it < 2; ++it)
#pragma unroll
    for (int nt = 0; nt < 4; ++nt) acc2[it][nt] = zero;

  // ---- attention steps: 4 x (32 j-columns) ----
  for (int js = 0; js < 4; ++js) {
    const int j0 = js * 32;
#pragma unroll
    for (int jsub = 0; jsub < 2; ++jsub) {
      const int j0s = j0 + jsub * 16;
      const ushort_t* kg = kw + (bt0 + j0s + lr) * DIMM + hoff + quad * 8;
      short8 kb0 = *(const short8*)(kg);
      short8 kb1 = *(const short8*)(kg + 32);
      const float mj = ms[j0s + lr];
#pragma unroll
      for (int it = 0; it < 2; ++it) {
        f32x4 s = __builtin_amdgcn_mfma_f32_16x16x32_bf16(qa[it][0], kb0, zero, 0, 0, 0);
        s = __builtin_amdgcn_mfma_f32_16x16x32_bf16(qa[it][1], kb1, s, 0, 0, 0);
#pragma unroll
        for (int r = 0; r < 4; ++r) {
          const int ig = i0 + it * 16 + quad * 4 + r;
          const int jg = j0s + lr;
          float w = (jg > ig) ? 0.f : s[r] * __expf(mi[it][r] - mj);
          pst[wv][it * 16 + quad * 4 + r][jsub * 16 + lr] = f2bf(w);
        }
      }
    }
    // GEMM2 accumulate this 32-wide K slab (LDS ops in-order within wave)
#pragma unroll
    for (int it = 0; it < 2; ++it) {
      short8 pa = *(const short8*)&pst[wv][it * 16 + lr][quad * 8];
#pragma unroll
      for (int nt = 0; nt < 4; ++nt) {
        short8 vb = *(const short8*)&vbt[nt * 16 + lr][j0 + quad * 8];
        acc2[it][nt] = __builtin_amdgcn_mfma_f32_16x16x32_bf16(pa, vb, acc2[it][nt], 0, 0, 0);
      }
    }
  }

  // ---- memory-term steps: 2 x (32 kd-columns): P = q*exp(m_i), V = E ----
#pragma unroll
  for (int es = 0; es < 2; ++es) {
    const int kd0 = es * 32;
    {
      const int row = lane >> 1;
      const int col0 = (lane & 1) * 16;
      const float ex = __expf(ms[i0 + row]);
      const ushort_t* qg = qw + (bt0 + i0 + row) * DIMM + hoff + kd0 + col0;
      uint4 u0 = *(const uint4*)(qg);
      uint4 u1 = *(const uint4*)(qg + 8);
      uint4 w0, w1;
      w0.x = pack2(blo(u0.x) * ex, bhi(u0.x) * ex);
      w0.y = pack2(blo(u0.y) * ex, bhi(u0.y) * ex);
      w0.z = pack2(blo(u0.z) * ex, bhi(u0.z) * ex);
      w0.w = pack2(blo(u0.w) * ex, bhi(u0.w) * ex);
      w1.x = pack2(blo(u1.x) * ex, bhi(u1.x) * ex);
      w1.y = pack2(blo(u1.y) * ex, bhi(u1.y) * ex);
      w1.z = pack2(blo(u1.z) * ex, bhi(u1.z) * ex);
      w1.w = pack2(blo(u1.w) * ex, bhi(u1.w) * ex);
      *(uint4*)&pst[wv][row][col0] = w0;
      *(uint4*)&pst[wv][row][col0 + 8] = w1;
    }
#pragma unroll
    for (int it = 0; it < 2; ++it) {
      short8 pa = *(const short8*)&pst[wv][it * 16 + lr][quad * 8];
#pragma unroll
      for (int nt = 0; nt < 4; ++nt) {
        short8 vb = *(const short8*)&vbt[nt * 16 + lr][128 + kd0 + quad * 8];
        acc2[it][nt] = __builtin_amdgcn_mfma_f32_16x16x32_bf16(pa, vb, acc2[it][nt], 0, 0, 0);
      }
    }
  }

  // ---- epilogue: C-layout scatter to y (fp32) ----
#pragma unroll
  for (int it = 0; it < 2; ++it) {
#pragma unroll
    for (int nt = 0; nt < 4; ++nt) {
      f32x4 a = acc2[it][nt];
#pragma unroll
      for (int r = 0; r < 4; ++r) {
        const int ig = i0 + it * 16 + quad * 4 + r;
        yout[(bt0 + ig) * DIMM + hoff + nt * 16 + lr] = a[r];
      }
    }
  }
}

// ---------------------------------------------------------------------------
extern "C" void kernel_launch(void* const* d_in, const int* in_sizes, int n_in,
                              void* d_out, int out_size, void* d_ws, size_t ws_size,
                              hipStream_t stream) {
  const float* x  = (const float*)d_in[0];
  const float* Wq = (const float*)d_in[1];
  const float* bq = (const float*)d_in[2];
  const float* Wk = (const float*)d_in[3];
  const float* bk = (const float*)d_in[4];
  const float* Wv = (const float*)d_in[5];
  const float* bv = (const float*)d_in[6];
  const float* Wb = (const float*)d_in[7];
  const float* bb = (const float*)d_in[8];
  const float* Wa = (const float*)d_in[9];
  const float* ba = (const float*)d_in[10];

  char* ws = (char*)d_ws;
  ushort_t* xb   = (ushort_t*)(ws + 0);           // 33554432 B
  ushort_t* wbm  = (ushort_t*)(ws + 33554432);    // 10485760 B
  float* bias_st = (float*)(ws + 44040192);       // 20480 B
  ushort_t* qw   = (ushort_t*)(ws + 44060672);    // 33554432 B
  ushort_t* kw   = (ushort_t*)(ws + 77615104);    // 33554432 B
  ushort_t* vw   = (ushort_t*)(ws + 111169536);   // 33554432 B
  ushort_t* bw   = (ushort_t*)(ws + 144723968);   // 33554432 B
  float* mArr    = (float*)(ws + 178278400);      // 1048576 B
  float* bmean   = (float*)(ws + 179326976);      // 1048576 B
  float* asum    = (float*)(ws + 180375552);      // 8192 B
  float* delta   = (float*)(ws + 180383744);      // 33554432 B
  float* Earr    = (float*)(ws + 213938176);      // 33554432 B  (total 247492608)

  float* yout = (float*)d_out;
  float* state_out = yout + (size_t)BT * DIMM;                 // + 16777216
  float* aout = state_out + (size_t)NBATCH * NHEAD * 64 * 64;  // + 262144

  k_cast<<<dim3(4096), dim3(256), 0, stream>>>(x, Wq, Wk, Wv, Wb, Wa,
                                               bq, bk, bv, bb, ba, xb, wbm, bias_st);
  k_proj<<<dim3(40, 128), dim3(256), 0, stream>>>(xb, wbm, bias_st, qw, kw, vw, bw, aout);
  k_stats<<<dim3(2048), dim3(128), 0, stream>>>(aout, bw, mArr, bmean, asum);
  k_delta<<<dim3(2048), dim3(256), 0, stream>>>(kw, vw, bmean, delta);
  k_scan<<<dim3(1024), dim3(256), 0, stream>>>(delta, asum, Earr, state_out);
  k_y<<<dim3(2048), dim3(256), 0, stream>>>(qw, kw, vw, bw, mArr, Earr, yout);
}